// Round 1
// baseline (328.759 us; speedup 1.0000x reference)
//
#include <hip/hip_runtime.h>

// MultiHeadVer2: B=2, T=4096, C=512, H=8, DH=64
// out = softmax(causal((x@Wq.T)(x@Wk.T)^T * C^-0.5)) @ (x@Wv.T) @ Wp.T + bp
//
// Strategy: bf16 MFMA everywhere (no fp32 MFMA on CDNA4), fp32 accum + fp32 softmax.
//   K1: convert x, Wq,Wk,Wv,Wp -> bf16 in ws
//   K2: QKV GEMM (y = x @ W.T), 128x128 tile, q pre-scaled by C^-0.5, scatter to (b,h,t,d)
//   K3: causal flash attention, BM=BN=64, online softmax, out bf16 (b,t,h,d)
//   K4: projection GEMM + bias, fp32 out

typedef unsigned short u16;
typedef __bf16 bf16;
typedef bf16 bf16x8 __attribute__((ext_vector_type(8)));
typedef float f32x4 __attribute__((ext_vector_type(4)));
typedef u16 u16x8 __attribute__((ext_vector_type(8)));

#define MFMA16(a, b, c) __builtin_amdgcn_mfma_f32_16x16x32_bf16(a, b, c, 0, 0, 0)

__device__ __forceinline__ u16 f2b(float f) {
  union { bf16 h; u16 u; } c;
  c.h = (bf16)f;  // RNE
  return c.u;
}

// ---------------------------------------------------------------------------
// K1: fp32 -> bf16 conversion. 8 elements per thread.
// Threads [0, 524288): x (4194304 elems). Then 4x32768 threads for the weights.
__global__ __launch_bounds__(256) void cvt_all(
    const float* __restrict__ x, const float* __restrict__ wq,
    const float* __restrict__ wk, const float* __restrict__ wv,
    const float* __restrict__ wp,
    u16* __restrict__ xb, u16* __restrict__ wqb, u16* __restrict__ wkb,
    u16* __restrict__ wvb, u16* __restrict__ wpb) {
  int i = blockIdx.x * 256 + threadIdx.x;
  const float* src;
  u16* dst;
  int off;
  if (i < 524288) {
    src = x; dst = xb; off = i * 8;
  } else {
    int j = i - 524288;            // 0..131071
    int wsel = j >> 15;            // 32768 threads per weight
    off = (j & 32767) * 8;
    src = (wsel == 0) ? wq : (wsel == 1) ? wk : (wsel == 2) ? wv : wp;
    dst = (wsel == 0) ? wqb : (wsel == 1) ? wkb : (wsel == 2) ? wvb : wpb;
  }
  float4 a = *(const float4*)&src[off];
  float4 b = *(const float4*)&src[off + 4];
  u16x8 o;
  o[0] = f2b(a.x); o[1] = f2b(a.y); o[2] = f2b(a.z); o[3] = f2b(a.w);
  o[4] = f2b(b.x); o[5] = f2b(b.y); o[6] = f2b(b.z); o[7] = f2b(b.w);
  *(u16x8*)&dst[off] = o;
}

// ---------------------------------------------------------------------------
// K2: QKV GEMM. y[m,n] = sum_k x[m,k]*W[n,k]. M=8192, N=512, K=512.
// 128x128 tile, BK=32, 256 threads = 4 waves (2x2 of 64x64).
// z selects W/out. q (z==0) pre-scaled by C^-0.5.
// Output scatter: out[((b*8+h)*4096 + t)*64 + d], b=m>>12, t=m&4095, h=n>>6, d=n&63.
#define AS_STRIDE 40  // 32 + 8 pad: b128 frag reads spread over all 32 banks
__global__ __launch_bounds__(256) void qkv_gemm(
    const u16* __restrict__ xb, const u16* __restrict__ wq,
    const u16* __restrict__ wk, const u16* __restrict__ wv,
    u16* __restrict__ qo, u16* __restrict__ ko, u16* __restrict__ vo) {
  __shared__ u16 As[128 * AS_STRIDE];
  __shared__ u16 Bs[128 * AS_STRIDE];
  const int z = blockIdx.z;
  const u16* W = (z == 0) ? wq : (z == 1) ? wk : wv;
  u16* O = (z == 0) ? qo : (z == 1) ? ko : vo;
  const int n0 = blockIdx.x * 128;
  const int m0 = blockIdx.y * 128;
  const int tid = threadIdx.x;
  const int lane = tid & 63;
  const int w = tid >> 6;
  const int wm = (w & 1) * 64;
  const int wn = (w >> 1) * 64;
  const int l15 = lane & 15, quad = lane >> 4;
  const int srow = tid >> 2;        // 0..63
  const int scol = (tid & 3) * 8;   // 0,8,16,24

  f32x4 acc[4][4] = {};

  for (int k0 = 0; k0 < 512; k0 += 32) {
    *(uint4*)&As[srow * AS_STRIDE + scol] =
        *(const uint4*)&xb[(m0 + srow) * 512 + k0 + scol];
    *(uint4*)&As[(srow + 64) * AS_STRIDE + scol] =
        *(const uint4*)&xb[(m0 + srow + 64) * 512 + k0 + scol];
    *(uint4*)&Bs[srow * AS_STRIDE + scol] =
        *(const uint4*)&W[(n0 + srow) * 512 + k0 + scol];
    *(uint4*)&Bs[(srow + 64) * AS_STRIDE + scol] =
        *(const uint4*)&W[(n0 + srow + 64) * 512 + k0 + scol];
    __syncthreads();
    bf16x8 af[4], bfv[4];
#pragma unroll
    for (int i = 0; i < 4; i++)
      af[i] = *(const bf16x8*)&As[(wm + i * 16 + l15) * AS_STRIDE + quad * 8];
#pragma unroll
    for (int j = 0; j < 4; j++)
      bfv[j] = *(const bf16x8*)&Bs[(wn + j * 16 + l15) * AS_STRIDE + quad * 8];
#pragma unroll
    for (int i = 0; i < 4; i++)
#pragma unroll
      for (int j = 0; j < 4; j++)
        acc[i][j] = MFMA16(af[i], bfv[j], acc[i][j]);
    __syncthreads();
  }

  const float scale = 0.044194173824159216f;  // C^-0.5
#pragma unroll
  for (int i = 0; i < 4; i++) {
    const int mrow = m0 + wm + i * 16 + quad * 4;
    const int b = mrow >> 12;
#pragma unroll
    for (int j = 0; j < 4; j++) {
      const int n = n0 + wn + j * 16 + l15;
      const int h = n >> 6, d = n & 63;
#pragma unroll
      for (int r = 0; r < 4; r++) {
        const int t = (mrow + r) & 4095;
        float fv = acc[i][j][r];
        if (z == 0) fv *= scale;
        O[((b * 8 + h) * 4096 + t) * 64 + d] = f2b(fv);
      }
    }
  }
}

// ---------------------------------------------------------------------------
// K3: causal flash attention. Grid (16 bh, 64 qtile). 256 threads = 4 waves,
// wave w owns 16 q-rows. BM=BN=64. q already scaled.
#define KV_STRIDE 72  // 64 + 8 pad
__global__ __launch_bounds__(256) void flash(
    const u16* __restrict__ qg, const u16* __restrict__ kg,
    const u16* __restrict__ vg, u16* __restrict__ ao) {
  __shared__ u16 Ks[64 * KV_STRIDE];
  __shared__ u16 Vt[64 * KV_STRIDE];          // transposed: Vt[d][kt]
  __shared__ u16 Ps[4][16 * KV_STRIDE];       // per-wave P strip
  const int bh = blockIdx.x;                  // 0..15
  const int qt = blockIdx.y;                  // 0..63
  const int tid = threadIdx.x, lane = tid & 63, w = tid >> 6;
  const int l15 = lane & 15, quad = lane >> 4;
  const int q0 = qt * 64;
  const int srow = tid >> 3;       // 0..31
  const int scol = (tid & 7) * 8;  // 0..56

  // Q fragments (A-operand layout), wave-private rows q0 + w*16 + [0,16)
  const u16* qbase = qg + (size_t)(bh * 4096 + q0 + w * 16) * 64;
  bf16x8 qf[2];
  qf[0] = *(const bf16x8*)&qbase[l15 * 64 + quad * 8];
  qf[1] = *(const bf16x8*)&qbase[l15 * 64 + 32 + quad * 8];

  f32x4 Oa[4] = {};
  float mrow[4] = {-1e30f, -1e30f, -1e30f, -1e30f};
  float lrow[4] = {0.f, 0.f, 0.f, 0.f};

  for (int j0 = 0; j0 <= q0; j0 += 64) {
    __syncthreads();  // protect LDS from previous iteration's readers
    // stage K tile (row-major, d contiguous)
    *(uint4*)&Ks[srow * KV_STRIDE + scol] =
        *(const uint4*)&kg[(size_t)(bh * 4096 + j0 + srow) * 64 + scol];
    *(uint4*)&Ks[(srow + 32) * KV_STRIDE + scol] =
        *(const uint4*)&kg[(size_t)(bh * 4096 + j0 + srow + 32) * 64 + scol];
    // stage V transposed: Vt[d][kt]
    {
      uint4 r0 = *(const uint4*)&vg[(size_t)(bh * 4096 + j0 + srow) * 64 + scol];
      uint4 r1 = *(const uint4*)&vg[(size_t)(bh * 4096 + j0 + srow + 32) * 64 + scol];
      const u16* e0 = (const u16*)&r0;
      const u16* e1 = (const u16*)&r1;
#pragma unroll
      for (int i = 0; i < 8; i++) Vt[(scol + i) * KV_STRIDE + srow] = e0[i];
#pragma unroll
      for (int i = 0; i < 8; i++) Vt[(scol + i) * KV_STRIDE + srow + 32] = e1[i];
    }
    __syncthreads();

    // S = Q K^T (16 x 64 strip per wave)
    f32x4 S[4] = {};
#pragma unroll
    for (int s = 0; s < 2; s++) {
#pragma unroll
      for (int jt = 0; jt < 4; jt++) {
        bf16x8 kf = *(const bf16x8*)&Ks[(jt * 16 + l15) * KV_STRIDE + s * 32 + quad * 8];
        S[jt] = MFMA16(qf[s], kf, S[jt]);
      }
    }

    // causal mask (only the diagonal tile has invalid cols)
    if (j0 == q0) {
      const int rowg = q0 + w * 16 + quad * 4;
#pragma unroll
      for (int jt = 0; jt < 4; jt++) {
        const int colg = j0 + jt * 16 + l15;
#pragma unroll
        for (int r = 0; r < 4; r++)
          if (colg > rowg + r) S[jt][r] = -1e30f;
      }
    }

    // online softmax: rows = quad*4 + r, cols spread over 16 lanes x 4 jt
    float al[4];
#pragma unroll
    for (int r = 0; r < 4; r++) {
      float m_ = fmaxf(fmaxf(S[0][r], S[1][r]), fmaxf(S[2][r], S[3][r]));
#pragma unroll
      for (int off = 1; off < 16; off <<= 1)
        m_ = fmaxf(m_, __shfl_xor(m_, off, 64));
      const float mn = fmaxf(mrow[r], m_);
      al[r] = __expf(mrow[r] - mn);
      mrow[r] = mn;
    }
    float rs[4] = {0.f, 0.f, 0.f, 0.f};
    u16 pb[4][4];
#pragma unroll
    for (int jt = 0; jt < 4; jt++)
#pragma unroll
      for (int r = 0; r < 4; r++) {
        float p = __expf(S[jt][r] - mrow[r]);
        rs[r] += p;
        pb[jt][r] = f2b(p);
      }
#pragma unroll
    for (int r = 0; r < 4; r++) {
      float s_ = rs[r];
#pragma unroll
      for (int off = 1; off < 16; off <<= 1) s_ += __shfl_xor(s_, off, 64);
      lrow[r] = lrow[r] * al[r] + s_;
#pragma unroll
      for (int dt = 0; dt < 4; dt++) Oa[dt][r] *= al[r];
    }

    // P -> LDS (C/D layout -> A-operand layout round trip)
#pragma unroll
    for (int jt = 0; jt < 4; jt++)
#pragma unroll
      for (int r = 0; r < 4; r++)
        Ps[w][(quad * 4 + r) * KV_STRIDE + jt * 16 + l15] = pb[jt][r];
    __syncthreads();

    // O += P V
#pragma unroll
    for (int s = 0; s < 2; s++) {
      bf16x8 pf = *(const bf16x8*)&Ps[w][l15 * KV_STRIDE + s * 32 + quad * 8];
#pragma unroll
      for (int dt = 0; dt < 4; dt++) {
        bf16x8 vf = *(const bf16x8*)&Vt[(dt * 16 + l15) * KV_STRIDE + s * 32 + quad * 8];
        Oa[dt] = MFMA16(pf, vf, Oa[dt]);
      }
    }
  }

  // epilogue: aout[(b*T + t)*512 + h*64 + d], bf16
  const int b_ = bh >> 3, h = bh & 7;
#pragma unroll
  for (int r = 0; r < 4; r++) {
    const float inv = 1.0f / lrow[r];
    const int t = q0 + w * 16 + quad * 4 + r;
#pragma unroll
    for (int dt = 0; dt < 4; dt++)
      ao[(size_t)(b_ * 4096 + t) * 512 + h * 64 + dt * 16 + l15] =
          f2b(Oa[dt][r] * inv);
  }
}

// ---------------------------------------------------------------------------
// K4: out = aout @ Wp.T + bp. fp32 output. Same tile structure as K2.
__global__ __launch_bounds__(256) void proj_gemm(
    const u16* __restrict__ A, const u16* __restrict__ Wb,
    const float* __restrict__ bias, float* __restrict__ out) {
  __shared__ u16 As[128 * AS_STRIDE];
  __shared__ u16 Bs[128 * AS_STRIDE];
  const int n0 = blockIdx.x * 128;
  const int m0 = blockIdx.y * 128;
  const int tid = threadIdx.x;
  const int lane = tid & 63;
  const int w = tid >> 6;
  const int wm = (w & 1) * 64;
  const int wn = (w >> 1) * 64;
  const int l15 = lane & 15, quad = lane >> 4;
  const int srow = tid >> 2;
  const int scol = (tid & 3) * 8;

  f32x4 acc[4][4] = {};

  for (int k0 = 0; k0 < 512; k0 += 32) {
    *(uint4*)&As[srow * AS_STRIDE + scol] =
        *(const uint4*)&A[(m0 + srow) * 512 + k0 + scol];
    *(uint4*)&As[(srow + 64) * AS_STRIDE + scol] =
        *(const uint4*)&A[(m0 + srow + 64) * 512 + k0 + scol];
    *(uint4*)&Bs[srow * AS_STRIDE + scol] =
        *(const uint4*)&Wb[(n0 + srow) * 512 + k0 + scol];
    *(uint4*)&Bs[(srow + 64) * AS_STRIDE + scol] =
        *(const uint4*)&Wb[(n0 + srow + 64) * 512 + k0 + scol];
    __syncthreads();
    bf16x8 af[4], bfv[4];
#pragma unroll
    for (int i = 0; i < 4; i++)
      af[i] = *(const bf16x8*)&As[(wm + i * 16 + l15) * AS_STRIDE + quad * 8];
#pragma unroll
    for (int j = 0; j < 4; j++)
      bfv[j] = *(const bf16x8*)&Bs[(wn + j * 16 + l15) * AS_STRIDE + quad * 8];
#pragma unroll
    for (int i = 0; i < 4; i++)
#pragma unroll
      for (int j = 0; j < 4; j++)
        acc[i][j] = MFMA16(af[i], bfv[j], acc[i][j]);
    __syncthreads();
  }

#pragma unroll
  for (int j = 0; j < 4; j++) {
    const int n = n0 + wn + j * 16 + l15;
    const float bn = bias[n];
#pragma unroll
    for (int i = 0; i < 4; i++) {
      const int mrow = m0 + wm + i * 16 + quad * 4;
#pragma unroll
      for (int r = 0; r < 4; r++)
        out[(size_t)(mrow + r) * 512 + n] = acc[i][j][r] + bn;
    }
  }
}

// ---------------------------------------------------------------------------
extern "C" void kernel_launch(void* const* d_in, const int* in_sizes, int n_in,
                              void* d_out, int out_size, void* d_ws,
                              size_t ws_size, hipStream_t stream) {
  const float* x  = (const float*)d_in[0];
  const float* Wq = (const float*)d_in[1];
  const float* Wk = (const float*)d_in[2];
  const float* Wv = (const float*)d_in[3];
  const float* Wp = (const float*)d_in[4];
  const float* bp = (const float*)d_in[5];

  char* ws = (char*)d_ws;
  u16* xb  = (u16*)(ws + 0);         // 8192x512 bf16
  u16* qb  = (u16*)(ws + 8388608);   // (b,h,t,d) bf16
  u16* kb  = (u16*)(ws + 16777216);
  u16* vb  = (u16*)(ws + 25165824);
  u16* ao  = (u16*)(ws + 33554432);  // (b,t,h*d) bf16
  u16* wqb = (u16*)(ws + 41943040);
  u16* wkb = (u16*)(ws + 41943040 + 524288);
  u16* wvb = (u16*)(ws + 41943040 + 2 * 524288);
  u16* wpb = (u16*)(ws + 41943040 + 3 * 524288);

  cvt_all<<<2560, 256, 0, stream>>>(x, Wq, Wk, Wv, Wp, xb, wqb, wkb, wvb, wpb);
  qkv_gemm<<<dim3(4, 64, 3), 256, 0, stream>>>(xb, wqb, wkb, wvb, qb, kb, vb);
  flash<<<dim3(16, 64), 256, 0, stream>>>(qb, kb, vb, ao);
  proj_gemm<<<dim3(4, 64), 256, 0, stream>>>(ao, wpb, bp, (float*)d_out);
}

// Round 3
// 268.252 us; speedup vs baseline: 1.2256x; 1.2256x over previous
//
#include <hip/hip_runtime.h>

// MultiHeadVer2: B=2, T=4096, C=512, H=8, DH=64
// out = softmax(causal((x@Wq.T)(x@Wk.T)^T * C^-0.5)) @ (x@Wv.T) @ Wp.T + bp
//
//   K1: convert x, Wq,Wk,Wv,Wp -> bf16 in ws
//   K2: QKV GEMM. q pre-scaled by C^-0.5*log2(e) (softmax uses exp2).
//       q,k -> (b,h,t,d) bf16; v -> TRANSPOSED (b,h,d,t) f16 for flash PV.
//   K3: causal flash attention, S^T trick: P stays in registers
//       (QK^T 16x16x32 bf16 -> C/D layout == A-layout of 16x16x16 f16 PV).
//       Block processes q-strip pair {qt, 63-qt}: uniform work, grid 16x32.
//   K4: projection GEMM + bias, fp32 out.

typedef unsigned short u16;
typedef __bf16 bf16;
typedef _Float16 f16;
typedef bf16 bf16x8 __attribute__((ext_vector_type(8)));
typedef f16 f16x4 __attribute__((ext_vector_type(4)));
typedef float f32x4 __attribute__((ext_vector_type(4)));
typedef u16 u16x8 __attribute__((ext_vector_type(8)));

#define MFMA_QK(a, b, c) __builtin_amdgcn_mfma_f32_16x16x32_bf16(a, b, c, 0, 0, 0)
#define MFMA_PV(a, b, c) __builtin_amdgcn_mfma_f32_16x16x16f16(a, b, c, 0, 0, 0)

// device exp2 (v_exp_f32 computes 2^x); avoid __exp2f which collides with glibc macros
extern "C" __device__ float __ocml_exp2_f32(float);
__device__ __forceinline__ float fast_exp2(float x) { return __ocml_exp2_f32(x); }

__device__ __forceinline__ u16 f2b(float f) {
  union { bf16 h; u16 u; } c;
  c.h = (bf16)f;
  return c.u;
}
__device__ __forceinline__ u16 f2h(float f) {
  union { f16 h; u16 u; } c;
  c.h = (f16)f;
  return c.u;
}

// ---------------------------------------------------------------------------
// K1: fp32 -> bf16 conversion. 8 elements per thread.
__global__ __launch_bounds__(256) void cvt_all(
    const float* __restrict__ x, const float* __restrict__ wq,
    const float* __restrict__ wk, const float* __restrict__ wv,
    const float* __restrict__ wp,
    u16* __restrict__ xb, u16* __restrict__ wqb, u16* __restrict__ wkb,
    u16* __restrict__ wvb, u16* __restrict__ wpb) {
  int i = blockIdx.x * 256 + threadIdx.x;
  const float* src;
  u16* dst;
  int off;
  if (i < 524288) {
    src = x; dst = xb; off = i * 8;
  } else {
    int j = i - 524288;
    int wsel = j >> 15;
    off = (j & 32767) * 8;
    src = (wsel == 0) ? wq : (wsel == 1) ? wk : (wsel == 2) ? wv : wp;
    dst = (wsel == 0) ? wqb : (wsel == 1) ? wkb : (wsel == 2) ? wvb : wpb;
  }
  float4 a = *(const float4*)&src[off];
  float4 b = *(const float4*)&src[off + 4];
  u16x8 o;
  o[0] = f2b(a.x); o[1] = f2b(a.y); o[2] = f2b(a.z); o[3] = f2b(a.w);
  o[4] = f2b(b.x); o[5] = f2b(b.y); o[6] = f2b(b.z); o[7] = f2b(b.w);
  *(u16x8*)&dst[off] = o;
}

// ---------------------------------------------------------------------------
// K2: QKV GEMM. y[m,n] = sum_k x[m,k]*W[n,k]. M=8192, N=512, K=512.
// z=0: q (scaled, bf16, bhtd), z=1: k (bf16, bhtd), z=2: v^T (f16, bhdt).
#define AS_STRIDE 40
__global__ __launch_bounds__(256) void qkv_gemm(
    const u16* __restrict__ xb, const u16* __restrict__ wq,
    const u16* __restrict__ wk, const u16* __restrict__ wv,
    u16* __restrict__ qo, u16* __restrict__ ko, u16* __restrict__ vto) {
  __shared__ u16 As[128 * AS_STRIDE];
  __shared__ u16 Bs[128 * AS_STRIDE];
  const int z = blockIdx.z;
  const u16* W = (z == 0) ? wq : (z == 1) ? wk : wv;
  const int n0 = blockIdx.x * 128;
  const int m0 = blockIdx.y * 128;
  const int tid = threadIdx.x;
  const int lane = tid & 63;
  const int w = tid >> 6;
  const int wm = (w & 1) * 64;
  const int wn = (w >> 1) * 64;
  const int l15 = lane & 15, quad = lane >> 4;
  const int srow = tid >> 2;
  const int scol = (tid & 3) * 8;

  f32x4 acc[4][4] = {};

  for (int k0 = 0; k0 < 512; k0 += 32) {
    *(uint4*)&As[srow * AS_STRIDE + scol] =
        *(const uint4*)&xb[(m0 + srow) * 512 + k0 + scol];
    *(uint4*)&As[(srow + 64) * AS_STRIDE + scol] =
        *(const uint4*)&xb[(m0 + srow + 64) * 512 + k0 + scol];
    *(uint4*)&Bs[srow * AS_STRIDE + scol] =
        *(const uint4*)&W[(n0 + srow) * 512 + k0 + scol];
    *(uint4*)&Bs[(srow + 64) * AS_STRIDE + scol] =
        *(const uint4*)&W[(n0 + srow + 64) * 512 + k0 + scol];
    __syncthreads();
    bf16x8 af[4], bfv[4];
#pragma unroll
    for (int i = 0; i < 4; i++)
      af[i] = *(const bf16x8*)&As[(wm + i * 16 + l15) * AS_STRIDE + quad * 8];
#pragma unroll
    for (int j = 0; j < 4; j++)
      bfv[j] = *(const bf16x8*)&Bs[(wn + j * 16 + l15) * AS_STRIDE + quad * 8];
#pragma unroll
    for (int i = 0; i < 4; i++)
#pragma unroll
      for (int j = 0; j < 4; j++)
        acc[i][j] = MFMA_QK(af[i], bfv[j], acc[i][j]);
    __syncthreads();
  }

  if (z < 2) {
    // q scale folds log2(e) so flash can use exp2: C^-0.5 * log2(e)
    const float scale =
        (z == 0) ? (0.044194173824159216f * 1.4426950408889634f) : 1.0f;
    u16* O = (z == 0) ? qo : ko;
#pragma unroll
    for (int i = 0; i < 4; i++) {
      const int mrow = m0 + wm + i * 16 + quad * 4;
      const int b = mrow >> 12;
#pragma unroll
      for (int j = 0; j < 4; j++) {
        const int n = n0 + wn + j * 16 + l15;
        const int h = n >> 6, d = n & 63;
#pragma unroll
        for (int r = 0; r < 4; r++) {
          const int t = (mrow + r) & 4095;
          O[((b * 8 + h) * 4096 + t) * 64 + d] = f2b(acc[i][j][r] * scale);
        }
      }
    }
  } else {
    // V^T: f16, layout ((b*8+h)*64 + d)*4096 + t
#pragma unroll
    for (int i = 0; i < 4; i++) {
      const int mrow = m0 + wm + i * 16 + quad * 4;
      const int b = mrow >> 12;
#pragma unroll
      for (int j = 0; j < 4; j++) {
        const int n = n0 + wn + j * 16 + l15;
        const int h = n >> 6, d = n & 63;
#pragma unroll
        for (int r = 0; r < 4; r++) {
          const int t = (mrow + r) & 4095;
          vto[(size_t)((b * 8 + h) * 64 + d) * 4096 + t] = f2h(acc[i][j][r]);
        }
      }
    }
  }
}

// ---------------------------------------------------------------------------
// K3: causal flash attention, S^T register-P design.
// Block = 4 waves, each wave owns 16 q rows; block processes strips
// {bp, 63-bp} sequentially -> uniform 65 j-tiles. Grid (16, 32).
#define KST 72  // row stride (u16): frag reads land 2-per-bank per 16-lane phase
__global__ __launch_bounds__(256) void flash(
    const u16* __restrict__ qg, const u16* __restrict__ kg,
    const u16* __restrict__ vtg, u16* __restrict__ ao) {
  __shared__ u16 Ks[64 * KST];  // K tile, bf16, [key][d]
  __shared__ u16 Vt[64 * KST];  // V^T tile, f16, [d][key]
  const int bh = blockIdx.x;
  const int bp = blockIdx.y;  // 0..31
  const int tid = threadIdx.x, lane = tid & 63, w = tid >> 6;
  const int l15 = lane & 15, quad = lane >> 4;
  const int srow = tid >> 3;       // 0..31
  const int seg = (tid & 7) * 8;   // 0..56
  const int b_ = bh >> 3, h = bh & 7;
  const u16* kbase = kg + (size_t)bh * 4096 * 64;
  const u16* vtbase = vtg + (size_t)bh * 64 * 4096;

#pragma unroll 1
  for (int pi = 0; pi < 2; pi++) {
    const int qt = pi ? (63 - bp) : bp;
    const int q0 = qt * 64;
    const int qb = q0 + w * 16;  // wave's first query row
    const u16* qbase = qg + (size_t)(bh * 4096 + qb) * 64;
    // Q b-frags: lane l15 = query, k = d
    bf16x8 qf0 = *(const bf16x8*)&qbase[l15 * 64 + quad * 8];
    bf16x8 qf1 = *(const bf16x8*)&qbase[l15 * 64 + 32 + quad * 8];
    f32x4 Oa[4] = {};                 // O[query=quad*4+r][d=dt*16+l15]
    float m_ = -1e30f, l_ = 0.f;      // per query=l15, replicated over quads

#pragma unroll 1
    for (int j0 = 0; j0 <= q0; j0 += 64) {
      __syncthreads();
      *(uint4*)&Ks[srow * KST + seg] =
          *(const uint4*)&kbase[(size_t)(j0 + srow) * 64 + seg];
      *(uint4*)&Ks[(srow + 32) * KST + seg] =
          *(const uint4*)&kbase[(size_t)(j0 + srow + 32) * 64 + seg];
      *(uint4*)&Vt[srow * KST + seg] =
          *(const uint4*)&vtbase[(size_t)srow * 4096 + j0 + seg];
      *(uint4*)&Vt[(srow + 32) * KST + seg] =
          *(const uint4*)&vtbase[(size_t)(srow + 32) * 4096 + j0 + seg];
      __syncthreads();

      // S^T = K·Q^T: D[key=jt*16+quad*4+r][query=l15]
      f32x4 S[4] = {};
#pragma unroll
      for (int jt = 0; jt < 4; jt++) {
        bf16x8 kf = *(const bf16x8*)&Ks[(jt * 16 + l15) * KST + quad * 8];
        S[jt] = MFMA_QK(kf, qf0, S[jt]);
      }
#pragma unroll
      for (int jt = 0; jt < 4; jt++) {
        bf16x8 kf = *(const bf16x8*)&Ks[(jt * 16 + l15) * KST + 32 + quad * 8];
        S[jt] = MFMA_QK(kf, qf1, S[jt]);
      }

      if (j0 == q0) {  // causal: mask key > query (only diagonal tile)
        const int query = qb + l15;
#pragma unroll
        for (int jt = 0; jt < 4; jt++) {
          const int key = j0 + jt * 16 + quad * 4;
#pragma unroll
          for (int r = 0; r < 4; r++)
            if (key + r > query) S[jt][r] = -1e30f;
        }
      }

      // online softmax (base-2; scale folded into q)
      float tmax = -1e30f;
#pragma unroll
      for (int jt = 0; jt < 4; jt++)
#pragma unroll
        for (int r = 0; r < 4; r++) tmax = fmaxf(tmax, S[jt][r]);
      tmax = fmaxf(tmax, __shfl_xor(tmax, 16, 64));
      tmax = fmaxf(tmax, __shfl_xor(tmax, 32, 64));
      const float mnew = fmaxf(m_, tmax);
      const float alpha = fast_exp2(m_ - mnew);
      m_ = mnew;

      float rsum = 0.f;
      f16x4 pf[4];  // P a-frags: lane l15 = query, k = quad*4 + r  (matches!)
#pragma unroll
      for (int jt = 0; jt < 4; jt++) {
#pragma unroll
        for (int r = 0; r < 4; r++) {
          const float p = fast_exp2(S[jt][r] - mnew);
          rsum += p;
          pf[jt][r] = (f16)p;
        }
      }
      rsum += __shfl_xor(rsum, 16, 64);
      rsum += __shfl_xor(rsum, 32, 64);
      l_ = l_ * alpha + rsum;

      // rescale O: need alpha indexed by query=quad*4+r -> width-16 shfl
#pragma unroll
      for (int r = 0; r < 4; r++) {
        const float ar = __shfl(alpha, quad * 4 + r, 16);
#pragma unroll
        for (int dt = 0; dt < 4; dt++) Oa[dt][r] *= ar;
      }

      // O += P·V via 16x16x16 f16 (P from regs, V^T b-frags from LDS)
#pragma unroll
      for (int kb = 0; kb < 4; kb++) {
#pragma unroll
        for (int dt = 0; dt < 4; dt++) {
          f16x4 vf =
              *(const f16x4*)&Vt[(dt * 16 + l15) * KST + kb * 16 + quad * 4];
          Oa[dt] = MFMA_PV(pf[kb], vf, Oa[dt]);
        }
      }
    }

    const float inv = 1.f / l_;
#pragma unroll
    for (int r = 0; r < 4; r++) {
      const float ir = __shfl(inv, quad * 4 + r, 16);
      const int t = qb + quad * 4 + r;
#pragma unroll
      for (int dt = 0; dt < 4; dt++)
        ao[(size_t)(b_ * 4096 + t) * 512 + h * 64 + dt * 16 + l15] =
            f2b(Oa[dt][r] * ir);
    }
  }
}

// ---------------------------------------------------------------------------
// K4: out = aout @ Wp.T + bp. fp32 output.
__global__ __launch_bounds__(256) void proj_gemm(
    const u16* __restrict__ A, const u16* __restrict__ Wb,
    const float* __restrict__ bias, float* __restrict__ out) {
  __shared__ u16 As[128 * AS_STRIDE];
  __shared__ u16 Bs[128 * AS_STRIDE];
  const int n0 = blockIdx.x * 128;
  const int m0 = blockIdx.y * 128;
  const int tid = threadIdx.x;
  const int lane = tid & 63;
  const int w = tid >> 6;
  const int wm = (w & 1) * 64;
  const int wn = (w >> 1) * 64;
  const int l15 = lane & 15, quad = lane >> 4;
  const int srow = tid >> 2;
  const int scol = (tid & 3) * 8;

  f32x4 acc[4][4] = {};

  for (int k0 = 0; k0 < 512; k0 += 32) {
    *(uint4*)&As[srow * AS_STRIDE + scol] =
        *(const uint4*)&A[(m0 + srow) * 512 + k0 + scol];
    *(uint4*)&As[(srow + 64) * AS_STRIDE + scol] =
        *(const uint4*)&A[(m0 + srow + 64) * 512 + k0 + scol];
    *(uint4*)&Bs[srow * AS_STRIDE + scol] =
        *(const uint4*)&Wb[(n0 + srow) * 512 + k0 + scol];
    *(uint4*)&Bs[(srow + 64) * AS_STRIDE + scol] =
        *(const uint4*)&Wb[(n0 + srow + 64) * 512 + k0 + scol];
    __syncthreads();
    bf16x8 af[4], bfv[4];
#pragma unroll
    for (int i = 0; i < 4; i++)
      af[i] = *(const bf16x8*)&As[(wm + i * 16 + l15) * AS_STRIDE + quad * 8];
#pragma unroll
    for (int j = 0; j < 4; j++)
      bfv[j] = *(const bf16x8*)&Bs[(wn + j * 16 + l15) * AS_STRIDE + quad * 8];
#pragma unroll
    for (int i = 0; i < 4; i++)
#pragma unroll
      for (int j = 0; j < 4; j++)
        acc[i][j] = MFMA_QK(af[i], bfv[j], acc[i][j]);
    __syncthreads();
  }

#pragma unroll
  for (int j = 0; j < 4; j++) {
    const int n = n0 + wn + j * 16 + l15;
    const float bn = bias[n];
#pragma unroll
    for (int i = 0; i < 4; i++) {
      const int mrow = m0 + wm + i * 16 + quad * 4;
#pragma unroll
      for (int r = 0; r < 4; r++)
        out[(size_t)(mrow + r) * 512 + n] = acc[i][j][r] + bn;
    }
  }
}

// ---------------------------------------------------------------------------
extern "C" void kernel_launch(void* const* d_in, const int* in_sizes, int n_in,
                              void* d_out, int out_size, void* d_ws,
                              size_t ws_size, hipStream_t stream) {
  const float* x  = (const float*)d_in[0];
  const float* Wq = (const float*)d_in[1];
  const float* Wk = (const float*)d_in[2];
  const float* Wv = (const float*)d_in[3];
  const float* Wp = (const float*)d_in[4];
  const float* bp = (const float*)d_in[5];

  char* ws = (char*)d_ws;
  u16* xb  = (u16*)(ws + 0);         // 8192x512 bf16
  u16* qb  = (u16*)(ws + 8388608);   // (b,h,t,d) bf16
  u16* kb  = (u16*)(ws + 16777216);  // (b,h,t,d) bf16
  u16* vtb = (u16*)(ws + 25165824);  // (b,h,d,t) f16
  u16* ao  = (u16*)(ws + 33554432);  // (b,t,h*d) bf16
  u16* wqb = (u16*)(ws + 41943040);
  u16* wkb = (u16*)(ws + 41943040 + 524288);
  u16* wvb = (u16*)(ws + 41943040 + 2 * 524288);
  u16* wpb = (u16*)(ws + 41943040 + 3 * 524288);

  cvt_all<<<2560, 256, 0, stream>>>(x, Wq, Wk, Wv, Wp, xb, wqb, wkb, wvb, wpb);
  qkv_gemm<<<dim3(4, 64, 3), 256, 0, stream>>>(xb, wqb, wkb, wvb, qb, kb, vtb);
  flash<<<dim3(16, 32), 256, 0, stream>>>(qb, kb, vtb, ao);
  proj_gemm<<<dim3(4, 64), 256, 0, stream>>>(ao, wpb, bp, (float*)d_out);
}